// Round 1
// baseline (637.915 us; speedup 1.0000x reference)
//
#include <hip/hip_runtime.h>
#include <cstdint>

#define B_ 4
#define T_ 2048
#define C_ 2048
#define H_ 16
#define HKV_ 4
#define D_ 128

typedef unsigned short u16;
typedef __bf16 bf16x8 __attribute__((ext_vector_type(8)));
typedef float f32x4 __attribute__((ext_vector_type(4)));

static __device__ __forceinline__ u16 f2bf(float f) {
  unsigned int x = __builtin_bit_cast(unsigned int, f);
  x += 0x7fffu + ((x >> 16) & 1u);
  return (u16)(x >> 16);
}
static __device__ __forceinline__ float bf2f(u16 u) {
  unsigned int x = ((unsigned int)u) << 16;
  return __builtin_bit_cast(float, x);
}

// ---------------- cast x fp32 -> bf16 ----------------
__global__ void cast_x_kernel(const float* __restrict__ in, u16* __restrict__ out, int n4) {
  int i = blockIdx.x * blockDim.x + threadIdx.x;
  if (i >= n4) return;
  float4 v = ((const float4*)in)[i];
  ushort4 o;
  o.x = f2bf(v.x); o.y = f2bf(v.y); o.z = f2bf(v.z); o.w = f2bf(v.w);
  ((ushort4*)out)[i] = o;
}

// ---------------- W (K,N) fp32 -> WT (N,K) bf16, LDS tiled ----------------
__global__ void wtrans_kernel(const float* __restrict__ W, u16* __restrict__ WT, int K, int N) {
  __shared__ float tile[64][65];
  int n0 = blockIdx.x * 64, k0 = blockIdx.y * 64;
  int tid = threadIdx.x;
#pragma unroll
  for (int i = 0; i < 16; i++) {
    int idx = i * 256 + tid;
    int r = idx >> 6, c = idx & 63;            // r: k, c: n
    tile[r][c] = W[(size_t)(k0 + r) * N + n0 + c];
  }
  __syncthreads();
#pragma unroll
  for (int i = 0; i < 16; i++) {
    int idx = i * 256 + tid;
    int r = idx >> 6, c = idx & 63;            // r: n, c: k
    WT[(size_t)(n0 + r) * K + k0 + c] = f2bf(tile[c][r]);
  }
}

// ---------------- GEMM: C(M,N) = A(M,K) * BT(N,K)^T, bf16 in, fp32 acc ----------------
template <bool F32OUT>
__global__ __launch_bounds__(256) void gemm_bt(const u16* __restrict__ A, const u16* __restrict__ BT,
                                               void* __restrict__ Cout, int M, int N, int K) {
  __shared__ __align__(16) u16 As[128 * 72];
  __shared__ __align__(16) u16 Bs[128 * 72];
  int tid = threadIdx.x;
  int w = tid >> 6, lane = tid & 63, quad = lane >> 4, lo = lane & 15;
  int wm = w >> 1, wn = w & 1;
  int m0 = blockIdx.y * 128, n0 = blockIdx.x * 128;
  f32x4 acc[4][4] = {};
  for (int k0 = 0; k0 < K; k0 += 64) {
#pragma unroll
    for (int i = 0; i < 4; i++) {
      int idx = i * 256 + tid;
      int r = idx >> 3, ch = idx & 7;
      *(int4*)(&As[r * 72 + ch * 8]) = *(const int4*)(&A[(size_t)(m0 + r) * K + k0 + ch * 8]);
      *(int4*)(&Bs[r * 72 + ch * 8]) = *(const int4*)(&BT[(size_t)(n0 + r) * K + k0 + ch * 8]);
    }
    __syncthreads();
#pragma unroll
    for (int kk = 0; kk < 2; kk++) {
      bf16x8 af[4], bfr[4];
#pragma unroll
      for (int mt = 0; mt < 4; mt++)
        af[mt] = *(const bf16x8*)(&As[(wm * 64 + mt * 16 + lo) * 72 + kk * 32 + quad * 8]);
#pragma unroll
      for (int nt = 0; nt < 4; nt++)
        bfr[nt] = *(const bf16x8*)(&Bs[(wn * 64 + nt * 16 + lo) * 72 + kk * 32 + quad * 8]);
#pragma unroll
      for (int mt = 0; mt < 4; mt++)
#pragma unroll
        for (int nt = 0; nt < 4; nt++)
          acc[mt][nt] = __builtin_amdgcn_mfma_f32_16x16x32_bf16(af[mt], bfr[nt], acc[mt][nt], 0, 0, 0);
    }
    __syncthreads();
  }
#pragma unroll
  for (int mt = 0; mt < 4; mt++)
#pragma unroll
    for (int nt = 0; nt < 4; nt++)
#pragma unroll
      for (int r = 0; r < 4; r++) {
        int mg = m0 + wm * 64 + mt * 16 + quad * 4 + r;
        int ng = n0 + wn * 64 + nt * 16 + lo;
        float v = acc[mt][nt][r];
        if (F32OUT) ((float*)Cout)[(size_t)mg * N + ng] = v;
        else ((u16*)Cout)[(size_t)mg * N + ng] = f2bf(v);
      }
}

// ---------------- RMSNorm + RoPE, (B,T,h,D) -> (B*h, T, D) ----------------
__global__ void rmsrope_kernel(const u16* __restrict__ in, const float* __restrict__ freqs,
                               u16* __restrict__ out, int heads) {
  int w = threadIdx.x >> 6, lane = threadIdx.x & 63;
  int row = blockIdx.x * 4 + w;                  // over B*T*heads
  int hh = row % heads;
  int rest = row / heads;
  int t = rest % T_;
  int b = rest / T_;
  const u16* ip = in + (size_t)row * D_;
  unsigned pr = *(const unsigned*)(&ip[2 * lane]);
  float t0 = bf2f((u16)(pr & 0xffff)), t1 = bf2f((u16)(pr >> 16));
  float ss = t0 * t0 + t1 * t1;
#pragma unroll
  for (int off = 32; off > 0; off >>= 1) ss += __shfl_xor(ss, off, 64);
  float scale = rsqrtf(ss * (1.0f / 128.0f) + 1e-6f);
  float2 cs = ((const float2*)freqs)[t * 64 + lane];
  float a = t0 * scale, c = t1 * scale;
  float o0 = a * cs.x - c * cs.y;
  float o1 = a * cs.y + c * cs.x;
  size_t ob = ((size_t)(b * heads + hh) * T_ + t) * D_ + 2 * lane;
  *(unsigned*)(&out[ob]) = ((unsigned)f2bf(o1) << 16) | (unsigned)f2bf(o0);
}

// ---------------- V transpose: (B,T,HKV,D) bf16 -> (B*HKV, D, T) bf16 ----------------
__global__ void vtrans_kernel(const u16* __restrict__ v, u16* __restrict__ vt) {
  __shared__ u16 tile[64][65];
  int bh = blockIdx.x;                     // b*HKV + h
  int b = bh >> 2, h = bh & 3;
  int t0 = blockIdx.y * 64, d0 = blockIdx.z * 64;
  const u16* base = v + ((size_t)b * T_ * HKV_ + h) * D_;
  u16* obase = vt + (size_t)bh * D_ * T_;
  int tid = threadIdx.x;
#pragma unroll
  for (int i = 0; i < 16; i++) {
    int idx = i * 256 + tid, tr = idx >> 6, dc = idx & 63;
    tile[tr][dc] = base[(size_t)(t0 + tr) * (HKV_ * D_) + d0 + dc];
  }
  __syncthreads();
#pragma unroll
  for (int i = 0; i < 16; i++) {
    int idx = i * 256 + tid, dr = idx >> 6, tc = idx & 63;
    obase[(size_t)(d0 + dr) * T_ + t0 + tc] = tile[tc][dr];
  }
}

// ---------------- Flash attention, causal, GQA ----------------
// qb: (B*H, T, D)  kb: (B*HKV, T, D)  vb: (B*HKV, D, T)  yb: (B, T, H, D)
__global__ __launch_bounds__(256) void flash_kernel(const u16* __restrict__ qb, const u16* __restrict__ kb,
                                                    const u16* __restrict__ vb, u16* __restrict__ yb) {
  __shared__ __align__(16) u16 Ks[64 * 136];
  __shared__ __align__(16) u16 Vs[128 * 72];
  __shared__ __align__(16) u16 Ps[4 * 16 * 72];
  int bh = blockIdx.x;                 // b*H + hq
  int b = bh >> 4, hq = bh & 15;
  int qt = gridDim.y - 1 - blockIdx.y; // heavy blocks first
  int tid = threadIdx.x, w = tid >> 6, lane = tid & 63, quad = lane >> 4, lo = lane & 15;
  int bhkv = b * HKV_ + (hq >> 2);
  const u16* qbase = qb + ((size_t)bh * T_ + qt * 64) * D_;
  const u16* kbase = kb + (size_t)bhkv * T_ * D_;
  const u16* vbase = vb + (size_t)bhkv * D_ * T_;

  bf16x8 qf[4];
#pragma unroll
  for (int kk = 0; kk < 4; kk++)
    qf[kk] = *(const bf16x8*)(&qbase[(w * 16 + lo) * D_ + kk * 32 + quad * 8]);

  f32x4 oacc[8] = {};
  float m_run[4], l_run[4];
#pragma unroll
  for (int r = 0; r < 4; r++) { m_run[r] = -1e30f; l_run[r] = 0.f; }
  const float sc = 0.08838834764831845f;   // 1/sqrt(128)

  for (int kt = 0; kt <= qt; kt++) {
#pragma unroll
    for (int i = 0; i < 4; i++) {          // stage K (64 keys x 128 d)
      int idx = i * 256 + tid, r = idx >> 4, ch = idx & 15;
      *(int4*)(&Ks[r * 136 + ch * 8]) = *(const int4*)(&kbase[(size_t)(kt * 64 + r) * D_ + ch * 8]);
    }
#pragma unroll
    for (int i = 0; i < 4; i++) {          // stage V^T (128 d x 64 keys)
      int idx = i * 256 + tid, d = idx >> 3, ch = idx & 7;
      *(int4*)(&Vs[d * 72 + ch * 8]) = *(const int4*)(&vbase[(size_t)d * T_ + kt * 64 + ch * 8]);
    }
    __syncthreads();

    f32x4 sacc[4];
#pragma unroll
    for (int nt = 0; nt < 4; nt++) {
      f32x4 a = {0.f, 0.f, 0.f, 0.f};
#pragma unroll
      for (int kk = 0; kk < 4; kk++) {
        bf16x8 bfr = *(const bf16x8*)(&Ks[(nt * 16 + lo) * 136 + kk * 32 + quad * 8]);
        a = __builtin_amdgcn_mfma_f32_16x16x32_bf16(qf[kk], bfr, a, 0, 0, 0);
      }
      sacc[nt] = a;
    }

    int qi = qt * 64 + w * 16 + quad * 4;  // + r
    int kjb = kt * 64 + lo;                // + nt*16
    float sv[4][4], rm[4], rs[4], alpha[4];
#pragma unroll
    for (int r = 0; r < 4; r++) rm[r] = -1e30f;
#pragma unroll
    for (int nt = 0; nt < 4; nt++)
#pragma unroll
      for (int r = 0; r < 4; r++) {
        float s = sacc[nt][r] * sc;
        if (kjb + nt * 16 > qi + r) s = -1e30f;
        sv[nt][r] = s;
        rm[r] = fmaxf(rm[r], s);
      }
#pragma unroll
    for (int off = 1; off < 16; off <<= 1)
#pragma unroll
      for (int r = 0; r < 4; r++) rm[r] = fmaxf(rm[r], __shfl_xor(rm[r], off, 64));
#pragma unroll
    for (int r = 0; r < 4; r++) {
      float mn = fmaxf(m_run[r], rm[r]);
      alpha[r] = __expf(m_run[r] - mn);
      m_run[r] = mn;
      rs[r] = 0.f;
    }
#pragma unroll
    for (int nt = 0; nt < 4; nt++)
#pragma unroll
      for (int r = 0; r < 4; r++) {
        float pv = __expf(sv[nt][r] - m_run[r]);
        sv[nt][r] = pv;
        rs[r] += pv;
      }
#pragma unroll
    for (int off = 1; off < 16; off <<= 1)
#pragma unroll
      for (int r = 0; r < 4; r++) rs[r] += __shfl_xor(rs[r], off, 64);
#pragma unroll
    for (int r = 0; r < 4; r++) l_run[r] = l_run[r] * alpha[r] + rs[r];
#pragma unroll
    for (int o = 0; o < 8; o++)
#pragma unroll
      for (int r = 0; r < 4; r++) oacc[o][r] *= alpha[r];
#pragma unroll
    for (int nt = 0; nt < 4; nt++)
#pragma unroll
      for (int r = 0; r < 4; r++)
        Ps[(w * 16 + quad * 4 + r) * 72 + nt * 16 + lo] = f2bf(sv[nt][r]);
    __syncthreads();
#pragma unroll
    for (int ks = 0; ks < 2; ks++) {
      bf16x8 pf = *(const bf16x8*)(&Ps[(w * 16 + lo) * 72 + ks * 32 + quad * 8]);
#pragma unroll
      for (int o = 0; o < 8; o++) {
        bf16x8 vf = *(const bf16x8*)(&Vs[(o * 16 + lo) * 72 + ks * 32 + quad * 8]);
        oacc[o] = __builtin_amdgcn_mfma_f32_16x16x32_bf16(pf, vf, oacc[o], 0, 0, 0);
      }
    }
    __syncthreads();
  }

#pragma unroll
  for (int o = 0; o < 8; o++)
#pragma unroll
    for (int r = 0; r < 4; r++) {
      int t = qt * 64 + w * 16 + quad * 4 + r;
      int d = o * 16 + lo;
      float v = oacc[o][r] / l_run[r];
      yb[(((size_t)b * T_ + t) * H_ + hq) * D_ + d] = f2bf(v);
    }
}

extern "C" void kernel_launch(void* const* d_in, const int* in_sizes, int n_in,
                              void* d_out, int out_size, void* d_ws, size_t ws_size,
                              hipStream_t stream) {
  const float* x = (const float*)d_in[0];
  const float* freqs = (const float*)d_in[1];
  const float* Wq = (const float*)d_in[2];
  const float* Wk = (const float*)d_in[3];
  const float* Wv = (const float*)d_in[4];
  const float* Wc = (const float*)d_in[5];
  float* out = (float*)d_out;

  char* ws = (char*)d_ws;
  size_t off = 0;
  auto alloc = [&](size_t bytes) { char* p = ws + off; off += (bytes + 255) & ~255ull; return p; };
  u16* xb  = (u16*)alloc((size_t)B_ * T_ * C_ * 2);          // 33.5 MB
  u16* WqT = (u16*)alloc((size_t)C_ * H_ * D_ * 2);          // 8.4 MB
  u16* WkT = (u16*)alloc((size_t)C_ * HKV_ * D_ * 2);        // 2.1 MB
  u16* WvT = (u16*)alloc((size_t)C_ * HKV_ * D_ * 2);        // 2.1 MB
  u16* WcT = (u16*)alloc((size_t)C_ * C_ * 2);               // 8.4 MB
  u16* qp  = (u16*)alloc((size_t)B_ * T_ * H_ * D_ * 2);     // 33.5 MB
  u16* kp  = (u16*)alloc((size_t)B_ * T_ * HKV_ * D_ * 2);   // 8.4 MB
  u16* vp  = (u16*)alloc((size_t)B_ * T_ * HKV_ * D_ * 2);   // 8.4 MB
  u16* qb  = (u16*)alloc((size_t)B_ * H_ * T_ * D_ * 2);     // 33.5 MB
  u16* kb  = (u16*)alloc((size_t)B_ * HKV_ * T_ * D_ * 2);   // 8.4 MB
  u16* vb  = (u16*)alloc((size_t)B_ * HKV_ * T_ * D_ * 2);   // 8.4 MB
  u16* yb  = (u16*)alloc((size_t)B_ * T_ * H_ * D_ * 2);     // 33.5 MB  (total ~181 MB)

  cast_x_kernel<<<dim3(B_ * T_ * C_ / 1024), dim3(256), 0, stream>>>(x, xb, B_ * T_ * C_ / 4);
  wtrans_kernel<<<dim3(32, 32), dim3(256), 0, stream>>>(Wq, WqT, C_, H_ * D_);
  wtrans_kernel<<<dim3(8, 32), dim3(256), 0, stream>>>(Wk, WkT, C_, HKV_ * D_);
  wtrans_kernel<<<dim3(8, 32), dim3(256), 0, stream>>>(Wv, WvT, C_, HKV_ * D_);
  wtrans_kernel<<<dim3(32, 32), dim3(256), 0, stream>>>(Wc, WcT, C_, C_);

  gemm_bt<false><<<dim3(16, 64), dim3(256), 0, stream>>>(xb, WqT, (void*)qp, 8192, 2048, 2048);
  gemm_bt<false><<<dim3(4, 64), dim3(256), 0, stream>>>(xb, WkT, (void*)kp, 8192, 512, 2048);
  gemm_bt<false><<<dim3(4, 64), dim3(256), 0, stream>>>(xb, WvT, (void*)vp, 8192, 512, 2048);

  rmsrope_kernel<<<dim3(B_ * T_ * H_ / 4), dim3(256), 0, stream>>>(qp, freqs, qb, H_);
  rmsrope_kernel<<<dim3(B_ * T_ * HKV_ / 4), dim3(256), 0, stream>>>(kp, freqs, kb, HKV_);
  vtrans_kernel<<<dim3(16, 32, 2), dim3(256), 0, stream>>>(vp, vb);

  flash_kernel<<<dim3(B_ * H_, T_ / 64), dim3(256), 0, stream>>>(qb, kb, vb, yb);

  gemm_bt<true><<<dim3(16, 64), dim3(256), 0, stream>>>(yb, WcT, (void*)out, 8192, 2048, 2048);
}

// Round 2
// 578.980 us; speedup vs baseline: 1.1018x; 1.1018x over previous
//
#include <hip/hip_runtime.h>
#include <cstdint>

#define B_ 4
#define T_ 2048
#define C_ 2048
#define H_ 16
#define HKV_ 4
#define D_ 128

typedef unsigned short u16;
typedef __bf16 bf16x8 __attribute__((ext_vector_type(8)));
typedef float f32x4 __attribute__((ext_vector_type(4)));

typedef __attribute__((address_space(1))) const void gvoid;
typedef __attribute__((address_space(3))) void lvoid;

static __device__ __forceinline__ void async_cp16(const u16* g, u16* l) {
  __builtin_amdgcn_global_load_lds((gvoid*)g, (lvoid*)l, 16, 0, 0);
}

static __device__ __forceinline__ u16 f2bf(float f) {
  unsigned int x = __builtin_bit_cast(unsigned int, f);
  x += 0x7fffu + ((x >> 16) & 1u);
  return (u16)(x >> 16);
}
static __device__ __forceinline__ float bf2f(u16 u) {
  unsigned int x = ((unsigned int)u) << 16;
  return __builtin_bit_cast(float, x);
}

// ---------------- cast x fp32 -> bf16 ----------------
__global__ void cast_x_kernel(const float* __restrict__ in, u16* __restrict__ out, int n4) {
  int i = blockIdx.x * blockDim.x + threadIdx.x;
  if (i >= n4) return;
  float4 v = ((const float4*)in)[i];
  ushort4 o;
  o.x = f2bf(v.x); o.y = f2bf(v.y); o.z = f2bf(v.z); o.w = f2bf(v.w);
  ((ushort4*)out)[i] = o;
}

// ---------------- W (K,N) fp32 -> WT (N,K) bf16, LDS tiled ----------------
__global__ void wtrans_kernel(const float* __restrict__ W, u16* __restrict__ WT, int K, int N) {
  __shared__ float tile[64][65];
  int n0 = blockIdx.x * 64, k0 = blockIdx.y * 64;
  int tid = threadIdx.x;
#pragma unroll
  for (int i = 0; i < 16; i++) {
    int idx = i * 256 + tid;
    int r = idx >> 6, c = idx & 63;            // r: k, c: n
    tile[r][c] = W[(size_t)(k0 + r) * N + n0 + c];
  }
  __syncthreads();
#pragma unroll
  for (int i = 0; i < 16; i++) {
    int idx = i * 256 + tid;
    int r = idx >> 6, c = idx & 63;            // r: n, c: k
    WT[(size_t)(n0 + r) * K + k0 + c] = f2bf(tile[c][r]);
  }
}

// ---------------- GEMM: C(M,N) = A(M,K) * BT(N,K)^T, bf16 in, fp32 acc ----------------
// m97 structure: global_load_lds width=16 staging into flat (unpadded) LDS tiles with
// XOR-swizzled 16B chunks: LDS[r][c] holds global chunk c^(r&7); reads XOR back.
template <bool F32OUT>
__global__ __launch_bounds__(256) void gemm_bt(const u16* __restrict__ A, const u16* __restrict__ BT,
                                               void* __restrict__ Cout, int M, int N, int K) {
  __shared__ __align__(16) u16 As[128 * 64];
  __shared__ __align__(16) u16 Bs[128 * 64];
  int tid = threadIdx.x;
  int w = tid >> 6, lane = tid & 63, quad = lane >> 4, lo = lane & 15;
  int wm = w >> 1, wn = w & 1;
  int m0 = blockIdx.y * 128, n0 = blockIdx.x * 128;
  // staging geometry: wave w, call c covers rows w*32+c*8 .. +8 (8 rows x 64 u16 = 1KB)
  int srow = w * 32 + (lane >> 3);            // + c*8
  int schunk = lane & 7;                      // 8-u16 chunk within row
  int gchunk = schunk ^ (lane >> 3);          // (srow+c*8)&7 == lane>>3
  f32x4 acc[4][4] = {};
  for (int k0 = 0; k0 < K; k0 += 64) {
#pragma unroll
    for (int c = 0; c < 4; c++) {
      int r = srow + c * 8;
      async_cp16(&A[(size_t)(m0 + r) * K + k0 + gchunk * 8], &As[r * 64 + schunk * 8]);
      async_cp16(&BT[(size_t)(n0 + r) * K + k0 + gchunk * 8], &Bs[r * 64 + schunk * 8]);
    }
    __syncthreads();
#pragma unroll
    for (int kk = 0; kk < 2; kk++) {
      bf16x8 af[4], bfr[4];
#pragma unroll
      for (int mt = 0; mt < 4; mt++) {
        int r = wm * 64 + mt * 16 + lo;
        af[mt] = *(const bf16x8*)(&As[r * 64 + (((kk * 4 + quad) ^ (lo & 7)) << 3)]);
      }
#pragma unroll
      for (int nt = 0; nt < 4; nt++) {
        int r = wn * 64 + nt * 16 + lo;
        bfr[nt] = *(const bf16x8*)(&Bs[r * 64 + (((kk * 4 + quad) ^ (lo & 7)) << 3)]);
      }
#pragma unroll
      for (int mt = 0; mt < 4; mt++)
#pragma unroll
        for (int nt = 0; nt < 4; nt++)
          acc[mt][nt] = __builtin_amdgcn_mfma_f32_16x16x32_bf16(af[mt], bfr[nt], acc[mt][nt], 0, 0, 0);
    }
    __syncthreads();
  }
#pragma unroll
  for (int mt = 0; mt < 4; mt++)
#pragma unroll
    for (int nt = 0; nt < 4; nt++)
#pragma unroll
      for (int r = 0; r < 4; r++) {
        int mg = m0 + wm * 64 + mt * 16 + quad * 4 + r;
        int ng = n0 + wn * 64 + nt * 16 + lo;
        float v = acc[mt][nt][r];
        if (F32OUT) ((float*)Cout)[(size_t)mg * N + ng] = v;
        else ((u16*)Cout)[(size_t)mg * N + ng] = f2bf(v);
      }
}

// ---------------- RMSNorm + RoPE, (B,T,h,D) -> (B*h, T, D), optional output scale ----------------
__global__ void rmsrope_kernel(const u16* __restrict__ in, const float* __restrict__ freqs,
                               u16* __restrict__ out, int heads, float outscale) {
  int w = threadIdx.x >> 6, lane = threadIdx.x & 63;
  int row = blockIdx.x * 4 + w;                  // over B*T*heads
  int hh = row % heads;
  int rest = row / heads;
  int t = rest % T_;
  int b = rest / T_;
  const u16* ip = in + (size_t)row * D_;
  unsigned pr = *(const unsigned*)(&ip[2 * lane]);
  float t0 = bf2f((u16)(pr & 0xffff)), t1 = bf2f((u16)(pr >> 16));
  float ss = t0 * t0 + t1 * t1;
#pragma unroll
  for (int off = 32; off > 0; off >>= 1) ss += __shfl_xor(ss, off, 64);
  float scale = rsqrtf(ss * (1.0f / 128.0f) + 1e-6f) * outscale;
  float2 cs = ((const float2*)freqs)[t * 64 + lane];
  float a = t0 * scale, c = t1 * scale;
  float o0 = a * cs.x - c * cs.y;
  float o1 = a * cs.y + c * cs.x;
  size_t ob = ((size_t)(b * heads + hh) * T_ + t) * D_ + 2 * lane;
  *(unsigned*)(&out[ob]) = ((unsigned)f2bf(o1) << 16) | (unsigned)f2bf(o0);
}

// ---------------- V transpose: (B,T,HKV,D) bf16 -> (B*HKV, D, T) bf16 ----------------
__global__ void vtrans_kernel(const u16* __restrict__ v, u16* __restrict__ vt) {
  __shared__ u16 tile[64][65];
  int bh = blockIdx.x;                     // b*HKV + h
  int b = bh >> 2, h = bh & 3;
  int t0 = blockIdx.y * 64, d0 = blockIdx.z * 64;
  const u16* base = v + ((size_t)b * T_ * HKV_ + h) * D_;
  u16* obase = vt + (size_t)bh * D_ * T_;
  int tid = threadIdx.x;
#pragma unroll
  for (int i = 0; i < 16; i++) {
    int idx = i * 256 + tid, tr = idx >> 6, dc = idx & 63;
    tile[tr][dc] = base[(size_t)(t0 + tr) * (HKV_ * D_) + d0 + dc];
  }
  __syncthreads();
#pragma unroll
  for (int i = 0; i < 16; i++) {
    int idx = i * 256 + tid, dr = idx >> 6, tc = idx & 63;
    obase[(size_t)(d0 + dr) * T_ + t0 + tc] = tile[tc][dr];
  }
}

// ---------------- Flash attention, causal, GQA ----------------
// Fixed-max softmax: after RMSNorm |q|=|k|=sqrt(D) so score <= sqrt(D)=11.32 < 12.
// Q is pre-scaled by 1/sqrt(D); p = exp2(s*log2e - 12*log2e). No running max, no
// rescale; l accumulated per-lane, reduced once after the loop.
// qb: (B*H, T, D)  kb: (B*HKV, T, D)  vb: (B*HKV, D, T)  yb: (B, T, H, D)
__global__ __launch_bounds__(256) void flash_kernel(const u16* __restrict__ qb, const u16* __restrict__ kb,
                                                    const u16* __restrict__ vb, u16* __restrict__ yb) {
  __shared__ __align__(16) u16 Ks[64 * 136];
  __shared__ __align__(16) u16 Vs[128 * 72];
  __shared__ __align__(16) u16 Ps[4 * 16 * 72];
  int bh = blockIdx.x;                 // b*H + hq
  int b = bh >> 4, hq = bh & 15;
  int qt = gridDim.y - 1 - blockIdx.y; // heavy blocks first
  int tid = threadIdx.x, w = tid >> 6, lane = tid & 63, quad = lane >> 4, lo = lane & 15;
  int bhkv = b * HKV_ + (hq >> 2);
  const u16* qbase = qb + ((size_t)bh * T_ + qt * 64) * D_;
  const u16* kbase = kb + (size_t)bhkv * T_ * D_;
  const u16* vbase = vb + (size_t)bhkv * D_ * T_;

  bf16x8 qf[4];
#pragma unroll
  for (int kk = 0; kk < 4; kk++)
    qf[kk] = *(const bf16x8*)(&qbase[(w * 16 + lo) * D_ + kk * 32 + quad * 8]);

  f32x4 oacc[8] = {};
  float l_part[4] = {0.f, 0.f, 0.f, 0.f};
  const float L2E = 1.4426950408889634f;
  const float NEG12L2E = -17.312340490667562f;   // -12*log2e

  for (int kt = 0; kt <= qt; kt++) {
#pragma unroll
    for (int i = 0; i < 4; i++) {          // stage K (64 keys x 128 d)
      int idx = i * 256 + tid, r = idx >> 4, ch = idx & 15;
      *(int4*)(&Ks[r * 136 + ch * 8]) = *(const int4*)(&kbase[(size_t)(kt * 64 + r) * D_ + ch * 8]);
    }
#pragma unroll
    for (int i = 0; i < 4; i++) {          // stage V^T (128 d x 64 keys)
      int idx = i * 256 + tid, d = idx >> 3, ch = idx & 7;
      *(int4*)(&Vs[d * 72 + ch * 8]) = *(const int4*)(&vbase[(size_t)d * T_ + kt * 64 + ch * 8]);
    }
    __syncthreads();

    f32x4 sacc[4];
#pragma unroll
    for (int nt = 0; nt < 4; nt++) {
      f32x4 a = {0.f, 0.f, 0.f, 0.f};
#pragma unroll
      for (int kk = 0; kk < 4; kk++) {
        bf16x8 bfr = *(const bf16x8*)(&Ks[(nt * 16 + lo) * 136 + kk * 32 + quad * 8]);
        a = __builtin_amdgcn_mfma_f32_16x16x32_bf16(qf[kk], bfr, a, 0, 0, 0);
      }
      sacc[nt] = a;
    }

    if (kt == qt) {                        // diagonal tile: causal mask (wave-uniform branch)
      int qi = qt * 64 + w * 16 + quad * 4;
      int kjb = kt * 64 + lo;
#pragma unroll
      for (int nt = 0; nt < 4; nt++)
#pragma unroll
        for (int r = 0; r < 4; r++)
          if (kjb + nt * 16 > qi + r) sacc[nt][r] = -1e30f;
    }

#pragma unroll
    for (int nt = 0; nt < 4; nt++)
#pragma unroll
      for (int r = 0; r < 4; r++) {
        float p = __builtin_amdgcn_exp2f(fmaf(sacc[nt][r], L2E, NEG12L2E));
        l_part[r] += p;
        Ps[(w * 16 + quad * 4 + r) * 72 + nt * 16 + lo] = f2bf(p);
      }
    __syncthreads();
#pragma unroll
    for (int ks = 0; ks < 2; ks++) {
      bf16x8 pf = *(const bf16x8*)(&Ps[(w * 16 + lo) * 72 + ks * 32 + quad * 8]);
#pragma unroll
      for (int o = 0; o < 8; o++) {
        bf16x8 vf = *(const bf16x8*)(&Vs[(o * 16 + lo) * 72 + ks * 32 + quad * 8]);
        oacc[o] = __builtin_amdgcn_mfma_f32_16x16x32_bf16(pf, vf, oacc[o], 0, 0, 0);
      }
    }
    __syncthreads();
  }

  // reduce l across the 16 lanes (lo) sharing each q-row
  float inv_l[4];
#pragma unroll
  for (int r = 0; r < 4; r++) {
    float l = l_part[r];
#pragma unroll
    for (int off = 1; off < 16; off <<= 1) l += __shfl_xor(l, off, 64);
    inv_l[r] = 1.0f / l;
  }

#pragma unroll
  for (int o = 0; o < 8; o++)
#pragma unroll
    for (int r = 0; r < 4; r++) {
      int t = qt * 64 + w * 16 + quad * 4 + r;
      int d = o * 16 + lo;
      float v = oacc[o][r] * inv_l[r];
      yb[(((size_t)b * T_ + t) * H_ + hq) * D_ + d] = f2bf(v);
    }
}

extern "C" void kernel_launch(void* const* d_in, const int* in_sizes, int n_in,
                              void* d_out, int out_size, void* d_ws, size_t ws_size,
                              hipStream_t stream) {
  const float* x = (const float*)d_in[0];
  const float* freqs = (const float*)d_in[1];
  const float* Wq = (const float*)d_in[2];
  const float* Wk = (const float*)d_in[3];
  const float* Wv = (const float*)d_in[4];
  const float* Wc = (const float*)d_in[5];
  float* out = (float*)d_out;

  char* ws = (char*)d_ws;
  size_t off = 0;
  auto alloc = [&](size_t bytes) { char* p = ws + off; off += (bytes + 255) & ~255ull; return p; };
  u16* xb  = (u16*)alloc((size_t)B_ * T_ * C_ * 2);
  u16* WqT = (u16*)alloc((size_t)C_ * H_ * D_ * 2);
  u16* WkT = (u16*)alloc((size_t)C_ * HKV_ * D_ * 2);
  u16* WvT = (u16*)alloc((size_t)C_ * HKV_ * D_ * 2);
  u16* WcT = (u16*)alloc((size_t)C_ * C_ * 2);
  u16* qp  = (u16*)alloc((size_t)B_ * T_ * H_ * D_ * 2);
  u16* kp  = (u16*)alloc((size_t)B_ * T_ * HKV_ * D_ * 2);
  u16* vp  = (u16*)alloc((size_t)B_ * T_ * HKV_ * D_ * 2);
  u16* qb  = (u16*)alloc((size_t)B_ * H_ * T_ * D_ * 2);
  u16* kb  = (u16*)alloc((size_t)B_ * HKV_ * T_ * D_ * 2);
  u16* vb  = (u16*)alloc((size_t)B_ * HKV_ * T_ * D_ * 2);
  u16* yb  = (u16*)alloc((size_t)B_ * T_ * H_ * D_ * 2);

  cast_x_kernel<<<dim3(B_ * T_ * C_ / 1024), dim3(256), 0, stream>>>(x, xb, B_ * T_ * C_ / 4);
  wtrans_kernel<<<dim3(32, 32), dim3(256), 0, stream>>>(Wq, WqT, C_, H_ * D_);
  wtrans_kernel<<<dim3(8, 32), dim3(256), 0, stream>>>(Wk, WkT, C_, HKV_ * D_);
  wtrans_kernel<<<dim3(8, 32), dim3(256), 0, stream>>>(Wv, WvT, C_, HKV_ * D_);
  wtrans_kernel<<<dim3(32, 32), dim3(256), 0, stream>>>(Wc, WcT, C_, C_);

  gemm_bt<false><<<dim3(16, 64), dim3(256), 0, stream>>>(xb, WqT, (void*)qp, 8192, 2048, 2048);
  gemm_bt<false><<<dim3(4, 64), dim3(256), 0, stream>>>(xb, WkT, (void*)kp, 8192, 512, 2048);
  gemm_bt<false><<<dim3(4, 64), dim3(256), 0, stream>>>(xb, WvT, (void*)vp, 8192, 512, 2048);

  const float sc = 0.08838834764831845f;  // 1/sqrt(128), folded into q
  rmsrope_kernel<<<dim3(B_ * T_ * H_ / 4), dim3(256), 0, stream>>>(qp, freqs, qb, H_, sc);
  rmsrope_kernel<<<dim3(B_ * T_ * HKV_ / 4), dim3(256), 0, stream>>>(kp, freqs, kb, HKV_, 1.0f);
  vtrans_kernel<<<dim3(16, 32, 2), dim3(256), 0, stream>>>(vp, vb);

  flash_kernel<<<dim3(B_ * H_, T_ / 64), dim3(256), 0, stream>>>(qb, kb, vb, yb);

  gemm_bt<true><<<dim3(16, 64), dim3(256), 0, stream>>>(yb, WcT, (void*)out, 8192, 2048, 2048);
}

// Round 3
// 541.364 us; speedup vs baseline: 1.1783x; 1.0695x over previous
//
#include <hip/hip_runtime.h>
#include <cstdint>

#define B_ 4
#define T_ 2048
#define C_ 2048
#define H_ 16
#define HKV_ 4
#define D_ 128

typedef unsigned short u16;
typedef __bf16 bf16x8 __attribute__((ext_vector_type(8)));
typedef float f32x4 __attribute__((ext_vector_type(4)));
typedef float f32x16 __attribute__((ext_vector_type(16)));

typedef __attribute__((address_space(1))) const void gvoid;
typedef __attribute__((address_space(3))) void lvoid;

static __device__ __forceinline__ void async_cp16(const u16* g, u16* l) {
  __builtin_amdgcn_global_load_lds((gvoid*)g, (lvoid*)l, 16, 0, 0);
}

static __device__ __forceinline__ u16 f2bf(float f) {
  unsigned int x = __builtin_bit_cast(unsigned int, f);
  x += 0x7fffu + ((x >> 16) & 1u);
  return (u16)(x >> 16);
}
static __device__ __forceinline__ float bf2f(u16 u) {
  unsigned int x = ((unsigned int)u) << 16;
  return __builtin_bit_cast(float, x);
}

// ---------------- cast x fp32 -> bf16 ----------------
__global__ void cast_x_kernel(const float* __restrict__ in, u16* __restrict__ out, int n4) {
  int i = blockIdx.x * blockDim.x + threadIdx.x;
  if (i >= n4) return;
  float4 v = ((const float4*)in)[i];
  ushort4 o;
  o.x = f2bf(v.x); o.y = f2bf(v.y); o.z = f2bf(v.z); o.w = f2bf(v.w);
  ((ushort4*)out)[i] = o;
}

// ---------------- W (K,N) fp32 -> WT (N,K) bf16, LDS tiled ----------------
__global__ void wtrans_kernel(const float* __restrict__ W, u16* __restrict__ WT, int K, int N) {
  __shared__ float tile[64][65];
  int n0 = blockIdx.x * 64, k0 = blockIdx.y * 64;
  int tid = threadIdx.x;
#pragma unroll
  for (int i = 0; i < 16; i++) {
    int idx = i * 256 + tid;
    int r = idx >> 6, c = idx & 63;            // r: k, c: n
    tile[r][c] = W[(size_t)(k0 + r) * N + n0 + c];
  }
  __syncthreads();
#pragma unroll
  for (int i = 0; i < 16; i++) {
    int idx = i * 256 + tid;
    int r = idx >> 6, c = idx & 63;            // r: n, c: k
    WT[(size_t)(n0 + r) * K + k0 + c] = f2bf(tile[c][r]);
  }
}

// ---------------- GEMM: C(M,N) = A(M,K) * BT(N,K)^T, bf16 in, fp32 acc ----------------
template <bool F32OUT>
__global__ __launch_bounds__(256) void gemm_bt(const u16* __restrict__ A, const u16* __restrict__ BT,
                                               void* __restrict__ Cout, int M, int N, int K) {
  __shared__ __align__(16) u16 As[128 * 64];
  __shared__ __align__(16) u16 Bs[128 * 64];
  int tid = threadIdx.x;
  int w = tid >> 6, lane = tid & 63, quad = lane >> 4, lo = lane & 15;
  int wm = w >> 1, wn = w & 1;
  int m0 = blockIdx.y * 128, n0 = blockIdx.x * 128;
  int srow = w * 32 + (lane >> 3);            // + c*8
  int schunk = lane & 7;
  int gchunk = schunk ^ (lane >> 3);
  f32x4 acc[4][4] = {};
  for (int k0 = 0; k0 < K; k0 += 64) {
#pragma unroll
    for (int c = 0; c < 4; c++) {
      int r = srow + c * 8;
      async_cp16(&A[(size_t)(m0 + r) * K + k0 + gchunk * 8], &As[r * 64 + schunk * 8]);
      async_cp16(&BT[(size_t)(n0 + r) * K + k0 + gchunk * 8], &Bs[r * 64 + schunk * 8]);
    }
    __syncthreads();
#pragma unroll
    for (int kk = 0; kk < 2; kk++) {
      bf16x8 af[4], bfr[4];
#pragma unroll
      for (int mt = 0; mt < 4; mt++) {
        int r = wm * 64 + mt * 16 + lo;
        af[mt] = *(const bf16x8*)(&As[r * 64 + (((kk * 4 + quad) ^ (lo & 7)) << 3)]);
      }
#pragma unroll
      for (int nt = 0; nt < 4; nt++) {
        int r = wn * 64 + nt * 16 + lo;
        bfr[nt] = *(const bf16x8*)(&Bs[r * 64 + (((kk * 4 + quad) ^ (lo & 7)) << 3)]);
      }
#pragma unroll
      for (int mt = 0; mt < 4; mt++)
#pragma unroll
        for (int nt = 0; nt < 4; nt++)
          acc[mt][nt] = __builtin_amdgcn_mfma_f32_16x16x32_bf16(af[mt], bfr[nt], acc[mt][nt], 0, 0, 0);
    }
    __syncthreads();
  }
#pragma unroll
  for (int mt = 0; mt < 4; mt++)
#pragma unroll
    for (int nt = 0; nt < 4; nt++)
#pragma unroll
      for (int r = 0; r < 4; r++) {
        int mg = m0 + wm * 64 + mt * 16 + quad * 4 + r;
        int ng = n0 + wn * 64 + nt * 16 + lo;
        float v = acc[mt][nt][r];
        if (F32OUT) ((float*)Cout)[(size_t)mg * N + ng] = v;
        else ((u16*)Cout)[(size_t)mg * N + ng] = f2bf(v);
      }
}

// ---------------- RMSNorm + RoPE, (B,T,h,D) -> (B*h, T, D), optional output scale ----------------
__global__ void rmsrope_kernel(const u16* __restrict__ in, const float* __restrict__ freqs,
                               u16* __restrict__ out, int heads, float outscale) {
  int w = threadIdx.x >> 6, lane = threadIdx.x & 63;
  int row = blockIdx.x * 4 + w;                  // over B*T*heads
  int hh = row % heads;
  int rest = row / heads;
  int t = rest % T_;
  int b = rest / T_;
  const u16* ip = in + (size_t)row * D_;
  unsigned pr = *(const unsigned*)(&ip[2 * lane]);
  float t0 = bf2f((u16)(pr & 0xffff)), t1 = bf2f((u16)(pr >> 16));
  float ss = t0 * t0 + t1 * t1;
#pragma unroll
  for (int off = 32; off > 0; off >>= 1) ss += __shfl_xor(ss, off, 64);
  float scale = rsqrtf(ss * (1.0f / 128.0f) + 1e-6f) * outscale;
  float2 cs = ((const float2*)freqs)[t * 64 + lane];
  float a = t0 * scale, c = t1 * scale;
  float o0 = a * cs.x - c * cs.y;
  float o1 = a * cs.y + c * cs.x;
  size_t ob = ((size_t)(b * heads + hh) * T_ + t) * D_ + 2 * lane;
  *(unsigned*)(&out[ob]) = ((unsigned)f2bf(o1) << 16) | (unsigned)f2bf(o0);
}

// ---------------- V transpose: (B,T,HKV,D) bf16 -> (B*HKV, D, T) bf16 ----------------
__global__ void vtrans_kernel(const u16* __restrict__ v, u16* __restrict__ vt) {
  __shared__ u16 tile[64][65];
  int bh = blockIdx.x;                     // b*HKV + h
  int b = bh >> 2, h = bh & 3;
  int t0 = blockIdx.y * 64, d0 = blockIdx.z * 64;
  const u16* base = v + ((size_t)b * T_ * HKV_ + h) * D_;
  u16* obase = vt + (size_t)bh * D_ * T_;
  int tid = threadIdx.x;
#pragma unroll
  for (int i = 0; i < 16; i++) {
    int idx = i * 256 + tid, tr = idx >> 6, dc = idx & 63;
    tile[tr][dc] = base[(size_t)(t0 + tr) * (HKV_ * D_) + d0 + dc];
  }
  __syncthreads();
#pragma unroll
  for (int i = 0; i < 16; i++) {
    int idx = i * 256 + tid, dr = idx >> 6, tc = idx & 63;
    obase[(size_t)(d0 + dr) * T_ + t0 + tc] = tile[tc][dr];
  }
}

// ---------------- Flash attention, causal, GQA ----------------
// 32x32x16 MFMAs. S^T = K.Q^T so query stays on lane&31; P^T built in registers
// via one shfl_xor(32) pair per k-step (no LDS round-trip). O^T = V^T.P^T.
// Fixed-max softmax (scores bounded by sqrt(D)<12 after RMSNorm; q pre-scaled 1/sqrt(D)).
// Per block: 128 q rows, 4 waves x 32 q each. K/V staged via swizzled global_load_lds.
// qb: (B*H, T, D)  kb: (B*HKV, T, D)  vb: (B*HKV, D, T)  yb: (B, T, H, D)
__global__ __launch_bounds__(256) void flash_kernel(const u16* __restrict__ qb, const u16* __restrict__ kb,
                                                    const u16* __restrict__ vb, u16* __restrict__ yb) {
  __shared__ __align__(16) u16 smem[17408];  // K:[0,8192) V:[8192,16384) u16; epilogue reuses [0,17408)
  u16* Ks = smem;              // 64 keys x 128 d, 16B chunks XOR-swizzled: chunk' = c ^ (row&7)
  u16* Vs = smem + 8192;       // 128 d x 64 keys, chunk' = c ^ (row&7)
  int bh = blockIdx.x;                 // b*H + hq
  int b = bh >> 4, hq = bh & 15;
  int qt = gridDim.y - 1 - blockIdx.y; // heavy blocks first
  int tid = threadIdx.x, w = tid >> 6, lane = tid & 63;
  int half = lane >> 5, lq = lane & 31;
  int bhkv = b * HKV_ + (hq >> 2);
  const u16* qbase = qb + ((size_t)bh * T_ + qt * 128) * D_;
  const u16* kbase = kb + (size_t)bhkv * T_ * D_;
  const u16* vbase = vb + (size_t)bhkv * D_ * T_;

  // Q B-frags: lane holds Q[w*32+lq][ds*16 + half*8 + j]
  bf16x8 qf[8];
#pragma unroll
  for (int ds = 0; ds < 8; ds++)
    qf[ds] = *(const bf16x8*)(&qbase[(w * 32 + lq) * D_ + ds * 16 + half * 8]);

  f32x16 oacc[4] = {};                 // O^T: 4 d-tiles of 32, col q = w*32+lq
  float l_part = 0.f;
  const float L2E = 1.4426950408889634f;
  const float N12 = -17.312340490667562f;  // -12*log2e

  int kchunk = lane & 15, krow0 = w * 16 + (lane >> 4);
  int vchunk = lane & 7, vrow0 = w * 32 + (lane >> 3);
  int qwave = qt * 128 + w * 32;       // first q row of this wave

  int ktmax = 2 * qt + 1;
  for (int kt = 0; kt <= ktmax; kt++) {
    const u16* ksrc = kbase + (size_t)(kt * 64) * D_;
    const u16* vsrc = vbase + kt * 64;
#pragma unroll
    for (int c = 0; c < 4; c++) {      // stage K: wave w rows [w*16, +16)
      int r = krow0 + c * 4;
      async_cp16(&ksrc[r * D_ + ((kchunk ^ (r & 7)) << 3)], &Ks[r * 128 + (kchunk << 3)]);
    }
#pragma unroll
    for (int c = 0; c < 4; c++) {      // stage V^T: wave w rows [w*32, +32)
      int r = vrow0 + c * 8;
      async_cp16(&vsrc[(size_t)r * T_ + ((vchunk ^ (r & 7)) << 3)], &Vs[r * 64 + (vchunk << 3)]);
    }
    __syncthreads();

#pragma unroll
    for (int t = 0; t < 2; t++) {
      int k0 = kt * 64 + t * 32;
      if (k0 > qwave + 31) continue;   // wave-uniform: whole 32-key sub-tile masked

      // S^T(32k x 32q) = K . Q^T
      f32x16 s = {};
#pragma unroll
      for (int ds = 0; ds < 8; ds++) {
        bf16x8 kf = *(const bf16x8*)(&Ks[(t * 32 + lq) * 128 + ((((ds << 1) + half) ^ (lq & 7)) << 3)]);
        s = __builtin_amdgcn_mfma_f32_32x32x16_bf16(kf, qf[ds], s, 0, 0, 0);
      }

      int qglob = qwave + lq;          // this lane's q (C col)
      if (k0 + 31 > qwave) {           // diagonal region: element-wise causal mask
#pragma unroll
        for (int i = 0; i < 16; i++) {
          int kl = k0 + 4 * half + (i & 3) + ((i >> 2) << 3);
          if (kl > qglob) s[i] = -1e30f;
        }
      }

      // p = exp2(s*log2e - 12*log2e); pack pairs (consecutive keys) to bf16x2
      unsigned pd[8];
#pragma unroll
      for (int j = 0; j < 8; j++) {
        float p0 = __builtin_amdgcn_exp2f(fmaf(s[2 * j], L2E, N12));
        float p1 = __builtin_amdgcn_exp2f(fmaf(s[2 * j + 1], L2E, N12));
        l_part += p0 + p1;
        pd[j] = ((unsigned)f2bf(p0)) | (((unsigned)f2bf(p1)) << 16);
      }

      // P^T B-frags: cross-half exchange. half0 holds keys {4h..}, needs partner's.
      unsigned s0 = (unsigned)__shfl_xor((int)(half ? pd[0] : pd[2]), 32, 64);
      unsigned s1 = (unsigned)__shfl_xor((int)(half ? pd[1] : pd[3]), 32, 64);
      unsigned s2 = (unsigned)__shfl_xor((int)(half ? pd[4] : pd[6]), 32, 64);
      unsigned s3 = (unsigned)__shfl_xor((int)(half ? pd[5] : pd[7]), 32, 64);
      uint4 f0 = half ? uint4{s0, s1, pd[2], pd[3]} : uint4{pd[0], pd[1], s0, s1};
      uint4 f1 = half ? uint4{s2, s3, pd[6], pd[7]} : uint4{pd[4], pd[5], s2, s3};

#pragma unroll
      for (int kstep = 0; kstep < 2; kstep++) {
        uint4 fr = kstep ? f1 : f0;
        bf16x8 pf = __builtin_bit_cast(bf16x8, fr);
        int cR = (t * 2 + kstep) * 2 + half;   // 16B chunk index into V row
#pragma unroll
        for (int dt = 0; dt < 4; dt++) {
          bf16x8 vf = *(const bf16x8*)(&Vs[(dt * 32 + lq) * 64 + ((cR ^ (lq & 7)) << 3)]);
          oacc[dt] = __builtin_amdgcn_mfma_f32_32x32x16_bf16(vf, pf, oacc[dt], 0, 0, 0);
        }
      }
    }
    __syncthreads();
  }

  // l: lane holds half the keys' partials for q=lq; combine with partner
  float lt = l_part + __shfl_xor(l_part, 32, 64);
  float inv = 1.0f / lt;

  // O^T -> LDS (q-major, stride 136) -> coalesced global write
  u16* Ep = smem;
#pragma unroll
  for (int dt = 0; dt < 4; dt++)
#pragma unroll
    for (int j = 0; j < 8; j++) {
      float p0 = oacc[dt][2 * j] * inv;
      float p1 = oacc[dt][2 * j + 1] * inv;
      unsigned pk = ((unsigned)f2bf(p0)) | (((unsigned)f2bf(p1)) << 16);
      int d = dt * 32 + 4 * half + 2 * (j & 1) + ((j >> 1) << 3);
      *(unsigned*)(&Ep[(w * 32 + lq) * 136 + d]) = pk;
    }
  __syncthreads();

  int ic = tid & 15, qr0 = tid >> 4;
  size_t orow = ((size_t)b * T_ + qt * 128) * 2048 + hq * 128;
#pragma unroll
  for (int j = 0; j < 8; j++) {
    int qr = qr0 + j * 16;
    uint4 v4 = *(const uint4*)(&Ep[qr * 136 + ic * 8]);
    *(uint4*)(&yb[orow + (size_t)qr * 2048 + ic * 8]) = v4;
  }
}

extern "C" void kernel_launch(void* const* d_in, const int* in_sizes, int n_in,
                              void* d_out, int out_size, void* d_ws, size_t ws_size,
                              hipStream_t stream) {
  const float* x = (const float*)d_in[0];
  const float* freqs = (const float*)d_in[1];
  const float* Wq = (const float*)d_in[2];
  const float* Wk = (const float*)d_in[3];
  const float* Wv = (const float*)d_in[4];
  const float* Wc = (const float*)d_in[5];
  float* out = (float*)d_out;

  char* ws = (char*)d_ws;
  size_t off = 0;
  auto alloc = [&](size_t bytes) { char* p = ws + off; off += (bytes + 255) & ~255ull; return p; };
  u16* xb  = (u16*)alloc((size_t)B_ * T_ * C_ * 2);
  u16* WqT = (u16*)alloc((size_t)C_ * H_ * D_ * 2);
  u16* WkT = (u16*)alloc((size_t)C_ * HKV_ * D_ * 2);
  u16* WvT = (u16*)alloc((size_t)C_ * HKV_ * D_ * 2);
  u16* WcT = (u16*)alloc((size_t)C_ * C_ * 2);
  u16* qp  = (u16*)alloc((size_t)B_ * T_ * H_ * D_ * 2);
  u16* kp  = (u16*)alloc((size_t)B_ * T_ * HKV_ * D_ * 2);
  u16* vp  = (u16*)alloc((size_t)B_ * T_ * HKV_ * D_ * 2);
  u16* qb  = (u16*)alloc((size_t)B_ * H_ * T_ * D_ * 2);
  u16* kb  = (u16*)alloc((size_t)B_ * HKV_ * T_ * D_ * 2);
  u16* vb  = (u16*)alloc((size_t)B_ * HKV_ * T_ * D_ * 2);
  u16* yb  = (u16*)alloc((size_t)B_ * T_ * H_ * D_ * 2);

  cast_x_kernel<<<dim3(B_ * T_ * C_ / 1024), dim3(256), 0, stream>>>(x, xb, B_ * T_ * C_ / 4);
  wtrans_kernel<<<dim3(32, 32), dim3(256), 0, stream>>>(Wq, WqT, C_, H_ * D_);
  wtrans_kernel<<<dim3(8, 32), dim3(256), 0, stream>>>(Wk, WkT, C_, HKV_ * D_);
  wtrans_kernel<<<dim3(8, 32), dim3(256), 0, stream>>>(Wv, WvT, C_, HKV_ * D_);
  wtrans_kernel<<<dim3(32, 32), dim3(256), 0, stream>>>(Wc, WcT, C_, C_);

  gemm_bt<false><<<dim3(16, 64), dim3(256), 0, stream>>>(xb, WqT, (void*)qp, 8192, 2048, 2048);
  gemm_bt<false><<<dim3(4, 64), dim3(256), 0, stream>>>(xb, WkT, (void*)kp, 8192, 512, 2048);
  gemm_bt<false><<<dim3(4, 64), dim3(256), 0, stream>>>(xb, WvT, (void*)vp, 8192, 512, 2048);

  const float sc = 0.08838834764831845f;  // 1/sqrt(128), folded into q
  rmsrope_kernel<<<dim3(B_ * T_ * H_ / 4), dim3(256), 0, stream>>>(qp, freqs, qb, H_, sc);
  rmsrope_kernel<<<dim3(B_ * T_ * HKV_ / 4), dim3(256), 0, stream>>>(kp, freqs, kb, HKV_, 1.0f);
  vtrans_kernel<<<dim3(16, 32, 2), dim3(256), 0, stream>>>(vp, vb);

  flash_kernel<<<dim3(B_ * H_, T_ / 128), dim3(256), 0, stream>>>(qb, kb, vb, yb);

  gemm_bt<true><<<dim3(16, 64), dim3(256), 0, stream>>>(yb, WcT, (void*)out, 8192, 2048, 2048);
}

// Round 4
// 478.901 us; speedup vs baseline: 1.3320x; 1.1304x over previous
//
#include <hip/hip_runtime.h>
#include <cstdint>

#define B_ 4
#define T_ 2048
#define C_ 2048
#define H_ 16
#define HKV_ 4
#define D_ 128

typedef unsigned short u16;
typedef __bf16 bf16x8 __attribute__((ext_vector_type(8)));
typedef float f32x4 __attribute__((ext_vector_type(4)));
typedef float f32x16 __attribute__((ext_vector_type(16)));

typedef __attribute__((address_space(1))) const void gvoid;
typedef __attribute__((address_space(3))) void lvoid;

static __device__ __forceinline__ void async_cp16(const u16* g, u16* l) {
  __builtin_amdgcn_global_load_lds((gvoid*)g, (lvoid*)l, 16, 0, 0);
}

static __device__ __forceinline__ u16 f2bf(float f) {
  unsigned int x = __builtin_bit_cast(unsigned int, f);
  x += 0x7fffu + ((x >> 16) & 1u);
  return (u16)(x >> 16);
}
static __device__ __forceinline__ float bf2f(u16 u) {
  unsigned int x = ((unsigned int)u) << 16;
  return __builtin_bit_cast(float, x);
}

// ---------------- cast x fp32 -> bf16 ----------------
__global__ void cast_x_kernel(const float* __restrict__ in, u16* __restrict__ out, int n4) {
  int i = blockIdx.x * blockDim.x + threadIdx.x;
  if (i >= n4) return;
  float4 v = ((const float4*)in)[i];
  ushort4 o;
  o.x = f2bf(v.x); o.y = f2bf(v.y); o.z = f2bf(v.z); o.w = f2bf(v.w);
  ((ushort4*)out)[i] = o;
}

// ---------------- all weight transposes in one dispatch ----------------
// Wq/Wk/Wv -> concatenated (3072, 2048) bf16 WT; Wc -> (2048, 2048) bf16 WT.
__global__ void wtrans_all_kernel(const float* __restrict__ Wq, const float* __restrict__ Wk,
                                  const float* __restrict__ Wv, const float* __restrict__ Wc,
                                  u16* __restrict__ Wcat, u16* __restrict__ WcT) {
  __shared__ float tile[64][65];
  int tb = blockIdx.x;
  const float* W; u16* WT; int Nw, t;
  if (tb < 1024)      { W = Wq; WT = Wcat;                         Nw = 2048; t = tb; }
  else if (tb < 1280) { W = Wk; WT = Wcat + (size_t)2048 * 2048;   Nw = 512;  t = tb - 1024; }
  else if (tb < 1536) { W = Wv; WT = Wcat + (size_t)2560 * 2048;   Nw = 512;  t = tb - 1280; }
  else                { W = Wc; WT = WcT;                          Nw = 2048; t = tb - 1536; }
  int ntiles = Nw >> 6;
  int n0 = (t % ntiles) * 64, k0 = (t / ntiles) * 64;
  int tid = threadIdx.x;
#pragma unroll
  for (int i = 0; i < 16; i++) {
    int idx = i * 256 + tid;
    int r = idx >> 6, c = idx & 63;
    tile[r][c] = W[(size_t)(k0 + r) * Nw + n0 + c];
  }
  __syncthreads();
#pragma unroll
  for (int i = 0; i < 16; i++) {
    int idx = i * 256 + tid;
    int r = idx >> 6, c = idx & 63;
    WT[(size_t)(n0 + r) * 2048 + k0 + c] = f2bf(tile[c][r]);
  }
}

// ---------------- GEMM: C(M,N) = A(M,K) * BT(N,K)^T, bf16 in, fp32 acc ----------------
template <bool F32OUT>
__global__ __launch_bounds__(256) void gemm_bt(const u16* __restrict__ A, const u16* __restrict__ BT,
                                               void* __restrict__ Cout, int M, int N, int K) {
  __shared__ __align__(16) u16 As[128 * 64];
  __shared__ __align__(16) u16 Bs[128 * 64];
  int tid = threadIdx.x;
  int w = tid >> 6, lane = tid & 63, quad = lane >> 4, lo = lane & 15;
  int wm = w >> 1, wn = w & 1;
  int m0 = blockIdx.y * 128, n0 = blockIdx.x * 128;
  int srow = w * 32 + (lane >> 3);            // + c*8
  int schunk = lane & 7;
  int gchunk = schunk ^ (lane >> 3);
  f32x4 acc[4][4] = {};
  for (int k0 = 0; k0 < K; k0 += 64) {
#pragma unroll
    for (int c = 0; c < 4; c++) {
      int r = srow + c * 8;
      async_cp16(&A[(size_t)(m0 + r) * K + k0 + gchunk * 8], &As[r * 64 + schunk * 8]);
      async_cp16(&BT[(size_t)(n0 + r) * K + k0 + gchunk * 8], &Bs[r * 64 + schunk * 8]);
    }
    __syncthreads();
#pragma unroll
    for (int kk = 0; kk < 2; kk++) {
      bf16x8 af[4], bfr[4];
#pragma unroll
      for (int mt = 0; mt < 4; mt++) {
        int r = wm * 64 + mt * 16 + lo;
        af[mt] = *(const bf16x8*)(&As[r * 64 + (((kk * 4 + quad) ^ (lo & 7)) << 3)]);
      }
#pragma unroll
      for (int nt = 0; nt < 4; nt++) {
        int r = wn * 64 + nt * 16 + lo;
        bfr[nt] = *(const bf16x8*)(&Bs[r * 64 + (((kk * 4 + quad) ^ (lo & 7)) << 3)]);
      }
#pragma unroll
      for (int mt = 0; mt < 4; mt++)
#pragma unroll
        for (int nt = 0; nt < 4; nt++)
          acc[mt][nt] = __builtin_amdgcn_mfma_f32_16x16x32_bf16(af[mt], bfr[nt], acc[mt][nt], 0, 0, 0);
    }
    __syncthreads();
  }
#pragma unroll
  for (int mt = 0; mt < 4; mt++)
#pragma unroll
    for (int nt = 0; nt < 4; nt++)
#pragma unroll
      for (int r = 0; r < 4; r++) {
        int mg = m0 + wm * 64 + mt * 16 + quad * 4 + r;
        int ng = n0 + wn * 64 + nt * 16 + lo;
        float v = acc[mt][nt][r];
        if (F32OUT) ((float*)Cout)[(size_t)mg * N + ng] = v;
        else ((u16*)Cout)[(size_t)mg * N + ng] = f2bf(v);
      }
}

// ---------------- RMSNorm + RoPE from packed qkv rows -> (B*h, T, D) ----------------
__global__ void rmsrope_kernel(const u16* __restrict__ in, const float* __restrict__ freqs,
                               u16* __restrict__ out, int heads, int instride, float outscale) {
  int w = threadIdx.x >> 6, lane = threadIdx.x & 63;
  int row = blockIdx.x * 4 + w;                  // over B*T*heads
  int hh = row % heads;
  int rest = row / heads;
  int t = rest % T_;
  int b = rest / T_;
  const u16* ip = in + (size_t)(b * T_ + t) * instride + hh * D_;
  unsigned pr = *(const unsigned*)(&ip[2 * lane]);
  float t0 = bf2f((u16)(pr & 0xffff)), t1 = bf2f((u16)(pr >> 16));
  float ss = t0 * t0 + t1 * t1;
#pragma unroll
  for (int off = 32; off > 0; off >>= 1) ss += __shfl_xor(ss, off, 64);
  float scale = rsqrtf(ss * (1.0f / 128.0f) + 1e-6f) * outscale;
  float2 cs = ((const float2*)freqs)[t * 64 + lane];
  float a = t0 * scale, c = t1 * scale;
  float o0 = a * cs.x - c * cs.y;
  float o1 = a * cs.y + c * cs.x;
  size_t ob = ((size_t)(b * heads + hh) * T_ + t) * D_ + 2 * lane;
  *(unsigned*)(&out[ob]) = ((unsigned)f2bf(o1) << 16) | (unsigned)f2bf(o0);
}

// ---------------- V transpose: packed qkv rows -> (B*HKV, D, T) bf16 ----------------
__global__ void vtrans_kernel(const u16* __restrict__ v, u16* __restrict__ vt) {
  __shared__ u16 tile[64][65];
  int bh = blockIdx.x;                     // b*HKV + h
  int b = bh >> 2, h = bh & 3;
  int t0 = blockIdx.y * 64, d0 = blockIdx.z * 64;
  const u16* base = v + (size_t)b * T_ * 3072 + h * D_;
  u16* obase = vt + (size_t)bh * D_ * T_;
  int tid = threadIdx.x;
#pragma unroll
  for (int i = 0; i < 16; i++) {
    int idx = i * 256 + tid, tr = idx >> 6, dc = idx & 63;
    tile[tr][dc] = base[(size_t)(t0 + tr) * 3072 + d0 + dc];
  }
  __syncthreads();
#pragma unroll
  for (int i = 0; i < 16; i++) {
    int idx = i * 256 + tid, dr = idx >> 6, tc = idx & 63;
    obase[(size_t)(d0 + dr) * T_ + t0 + tc] = tile[tc][dr];
  }
}

// ---------------- Flash attention, causal, GQA, triangle-paired ----------------
// Block (bh, j) processes q-tiles {15-j, j}: uniform 34 kt-iters/block, 512 blocks.
// S^T = K.Q^T (query on lane&31); P^T built in registers via shfl_xor(32); O^T = V^T.P^T.
// Fixed-max softmax (|score|<=sqrt(D)<12, q pre-scaled by 1/sqrt(D)); v_perm bf16 packing.
__global__ __launch_bounds__(256) void flash_kernel(const u16* __restrict__ qb, const u16* __restrict__ kb,
                                                    const u16* __restrict__ vb, u16* __restrict__ yb) {
  __shared__ __align__(16) u16 smem[17408];  // K:[0,8192) V:[8192,16384); epilogue reuses all
  u16* Ks = smem;              // 64 keys x 128 d, 16B chunks XOR-swizzled: chunk' = c ^ (row&7)
  u16* Vs = smem + 8192;       // 128 d x 64 keys, chunk' = c ^ (row&7)
  int bh = blockIdx.x;                 // b*H + hq
  int b = bh >> 4, hq = bh & 15;
  int jp = blockIdx.y;                 // 0..7 pair index
  int tid = threadIdx.x, w = tid >> 6, lane = tid & 63;
  int half = lane >> 5, lq = lane & 31;
  int bhkv = b * HKV_ + (hq >> 2);
  const u16* kbase = kb + (size_t)bhkv * T_ * D_;
  const u16* vbase = vb + (size_t)bhkv * D_ * T_;
  const float L2E = 1.4426950408889634f;
  const float N12 = -17.312340490667562f;  // -12*log2e

  int kchunk = lane & 15, krow0 = w * 16 + (lane >> 4);
  int vchunk = lane & 7, vrow0 = w * 32 + (lane >> 3);

  for (int ph = 0; ph < 2; ph++) {
    int qt = ph ? jp : (15 - jp);      // heavy tile first
    const u16* qbase = qb + ((size_t)bh * T_ + qt * 128) * D_;
    int qwave = qt * 128 + w * 32;

    bf16x8 qf[8];
#pragma unroll
    for (int ds = 0; ds < 8; ds++)
      qf[ds] = *(const bf16x8*)(&qbase[(w * 32 + lq) * D_ + ds * 16 + half * 8]);

    f32x16 oacc[4] = {};
    float l_part = 0.f;

    int ktmax = 2 * qt + 1;
    for (int kt = 0; kt <= ktmax; kt++) {
      const u16* ksrc = kbase + (size_t)(kt * 64) * D_;
      const u16* vsrc = vbase + kt * 64;
#pragma unroll
      for (int c = 0; c < 4; c++) {
        int r = krow0 + c * 4;
        async_cp16(&ksrc[r * D_ + ((kchunk ^ (r & 7)) << 3)], &Ks[r * 128 + (kchunk << 3)]);
      }
#pragma unroll
      for (int c = 0; c < 4; c++) {
        int r = vrow0 + c * 8;
        async_cp16(&vsrc[(size_t)r * T_ + ((vchunk ^ (r & 7)) << 3)], &Vs[r * 64 + (vchunk << 3)]);
      }
      __syncthreads();

#pragma unroll
      for (int t = 0; t < 2; t++) {
        int k0 = kt * 64 + t * 32;
        if (k0 > qwave + 31) continue;   // wave-uniform: sub-tile fully masked

        f32x16 s = {};
#pragma unroll
        for (int ds = 0; ds < 8; ds++) {
          bf16x8 kf = *(const bf16x8*)(&Ks[(t * 32 + lq) * 128 + ((((ds << 1) + half) ^ (lq & 7)) << 3)]);
          s = __builtin_amdgcn_mfma_f32_32x32x16_bf16(kf, qf[ds], s, 0, 0, 0);
        }

        int qglob = qwave + lq;
        if (k0 + 31 > qwave) {           // diagonal region: element-wise causal mask
#pragma unroll
          for (int i = 0; i < 16; i++) {
            int kl = k0 + 4 * half + (i & 3) + ((i >> 2) << 3);
            if (kl > qglob) s[i] = -1e30f;
          }
        }

        unsigned pd[8];
#pragma unroll
        for (int j2 = 0; j2 < 8; j2++) {
          float p0 = __builtin_amdgcn_exp2f(fmaf(s[2 * j2], L2E, N12));
          float p1 = __builtin_amdgcn_exp2f(fmaf(s[2 * j2 + 1], L2E, N12));
          l_part += p0 + p1;
          pd[j2] = __builtin_amdgcn_perm(__builtin_bit_cast(unsigned, p1),
                                         __builtin_bit_cast(unsigned, p0), 0x07060302u);
        }

        unsigned s0 = (unsigned)__shfl_xor((int)(half ? pd[0] : pd[2]), 32, 64);
        unsigned s1 = (unsigned)__shfl_xor((int)(half ? pd[1] : pd[3]), 32, 64);
        unsigned s2 = (unsigned)__shfl_xor((int)(half ? pd[4] : pd[6]), 32, 64);
        unsigned s3 = (unsigned)__shfl_xor((int)(half ? pd[5] : pd[7]), 32, 64);
        uint4 f0 = half ? uint4{s0, s1, pd[2], pd[3]} : uint4{pd[0], pd[1], s0, s1};
        uint4 f1 = half ? uint4{s2, s3, pd[6], pd[7]} : uint4{pd[4], pd[5], s2, s3};

#pragma unroll
        for (int kstep = 0; kstep < 2; kstep++) {
          uint4 fr = kstep ? f1 : f0;
          bf16x8 pf = __builtin_bit_cast(bf16x8, fr);
          int cR = (t * 2 + kstep) * 2 + half;
#pragma unroll
          for (int dt = 0; dt < 4; dt++) {
            bf16x8 vf = *(const bf16x8*)(&Vs[(dt * 32 + lq) * 64 + ((cR ^ (lq & 7)) << 3)]);
            oacc[dt] = __builtin_amdgcn_mfma_f32_32x32x16_bf16(vf, pf, oacc[dt], 0, 0, 0);
          }
        }
      }
      __syncthreads();
    }

    float lt = l_part + __shfl_xor(l_part, 32, 64);
    float inv = 1.0f / lt;

    u16* Ep = smem;
#pragma unroll
    for (int dt = 0; dt < 4; dt++)
#pragma unroll
      for (int j2 = 0; j2 < 8; j2++) {
        float p0 = oacc[dt][2 * j2] * inv;
        float p1 = oacc[dt][2 * j2 + 1] * inv;
        unsigned pk = ((unsigned)f2bf(p0)) | (((unsigned)f2bf(p1)) << 16);
        int d = dt * 32 + 4 * half + 2 * (j2 & 1) + ((j2 >> 1) << 3);
        *(unsigned*)(&Ep[(w * 32 + lq) * 136 + d]) = pk;
      }
    __syncthreads();

    int ic = tid & 15, qr0 = tid >> 4;
    size_t orow = ((size_t)b * T_ + qt * 128) * 2048 + hq * 128;
#pragma unroll
    for (int j2 = 0; j2 < 8; j2++) {
      int qr = qr0 + j2 * 16;
      uint4 v4 = *(const uint4*)(&Ep[qr * 136 + ic * 8]);
      *(uint4*)(&yb[orow + (size_t)qr * 2048 + ic * 8]) = v4;
    }
    __syncthreads();   // protect Ep before next phase's staging overwrites smem
  }
}

extern "C" void kernel_launch(void* const* d_in, const int* in_sizes, int n_in,
                              void* d_out, int out_size, void* d_ws, size_t ws_size,
                              hipStream_t stream) {
  const float* x = (const float*)d_in[0];
  const float* freqs = (const float*)d_in[1];
  const float* Wq = (const float*)d_in[2];
  const float* Wk = (const float*)d_in[3];
  const float* Wv = (const float*)d_in[4];
  const float* Wc = (const float*)d_in[5];
  float* out = (float*)d_out;

  char* ws = (char*)d_ws;
  size_t off = 0;
  auto alloc = [&](size_t bytes) { char* p = ws + off; off += (bytes + 255) & ~255ull; return p; };
  u16* xb   = (u16*)alloc((size_t)B_ * T_ * C_ * 2);
  u16* Wcat = (u16*)alloc((size_t)C_ * 3072 * 2);
  u16* WcT  = (u16*)alloc((size_t)C_ * C_ * 2);
  u16* qkvp = (u16*)alloc((size_t)B_ * T_ * 3072 * 2);
  u16* qb   = (u16*)alloc((size_t)B_ * H_ * T_ * D_ * 2);
  u16* kb   = (u16*)alloc((size_t)B_ * HKV_ * T_ * D_ * 2);
  u16* vb   = (u16*)alloc((size_t)B_ * HKV_ * T_ * D_ * 2);
  u16* yb   = (u16*)alloc((size_t)B_ * T_ * H_ * D_ * 2);

  cast_x_kernel<<<dim3(B_ * T_ * C_ / 1024), dim3(256), 0, stream>>>(x, xb, B_ * T_ * C_ / 4);
  wtrans_all_kernel<<<dim3(2560), dim3(256), 0, stream>>>(Wq, Wk, Wv, Wc, Wcat, WcT);

  gemm_bt<false><<<dim3(24, 64), dim3(256), 0, stream>>>(xb, Wcat, (void*)qkvp, 8192, 3072, 2048);

  const float sc = 0.08838834764831845f;  // 1/sqrt(128), folded into q
  rmsrope_kernel<<<dim3(B_ * T_ * H_ / 4), dim3(256), 0, stream>>>(qkvp, freqs, qb, H_, 3072, sc);
  rmsrope_kernel<<<dim3(B_ * T_ * HKV_ / 4), dim3(256), 0, stream>>>(qkvp + 2048, freqs, kb, HKV_, 3072, 1.0f);
  vtrans_kernel<<<dim3(16, 32, 2), dim3(256), 0, stream>>>(qkvp + 2560, vb);

  flash_kernel<<<dim3(B_ * H_, 8), dim3(256), 0, stream>>>(qb, kb, vb, yb);

  gemm_bt<true><<<dim3(16, 64), dim3(256), 0, stream>>>(yb, WcT, (void*)out, 8192, 2048, 2048);
}

// Round 5
// 465.060 us; speedup vs baseline: 1.3717x; 1.0298x over previous
//
#include <hip/hip_runtime.h>
#include <cstdint>

#define B_ 4
#define T_ 2048
#define C_ 2048
#define H_ 16
#define HKV_ 4
#define D_ 128

typedef unsigned short u16;
typedef __bf16 bf16x8 __attribute__((ext_vector_type(8)));
typedef float f32x4 __attribute__((ext_vector_type(4)));
typedef float f32x16 __attribute__((ext_vector_type(16)));

typedef __attribute__((address_space(1))) const void gvoid;
typedef __attribute__((address_space(3))) void lvoid;

static __device__ __forceinline__ void async_cp16(const u16* g, u16* l) {
  __builtin_amdgcn_global_load_lds((gvoid*)g, (lvoid*)l, 16, 0, 0);
}

static __device__ __forceinline__ u16 f2bf(float f) {
  unsigned int x = __builtin_bit_cast(unsigned int, f);
  x += 0x7fffu + ((x >> 16) & 1u);
  return (u16)(x >> 16);
}

// ---------------- prep: cast x fp32->bf16 (blocks 0..4095) + weight transposes ----------------
__global__ void prep_kernel(const float* __restrict__ x, const float* __restrict__ Wq,
                            const float* __restrict__ Wk, const float* __restrict__ Wv,
                            const float* __restrict__ Wc, u16* __restrict__ xb,
                            u16* __restrict__ Wcat, u16* __restrict__ WcT) {
  __shared__ float tile[64][65];
  int tb = blockIdx.x, tid = threadIdx.x;
  if (tb < 4096) {                       // cast: 4096 blocks x 1024 float4
    const float4* in4 = (const float4*)x;
#pragma unroll
    for (int j = 0; j < 4; j++) {
      int i = tb * 1024 + j * 256 + tid;
      float4 v = in4[i];
      ushort4 o;
      o.x = f2bf(v.x); o.y = f2bf(v.y); o.z = f2bf(v.z); o.w = f2bf(v.w);
      ((ushort4*)xb)[i] = o;
    }
    return;
  }
  int tb2 = tb - 4096;
  const float* W; u16* WT; int Nw, t;
  if (tb2 < 1024)      { W = Wq; WT = Wcat;                       Nw = 2048; t = tb2; }
  else if (tb2 < 1280) { W = Wk; WT = Wcat + (size_t)2048 * 2048; Nw = 512;  t = tb2 - 1024; }
  else if (tb2 < 1536) { W = Wv; WT = Wcat + (size_t)2560 * 2048; Nw = 512;  t = tb2 - 1280; }
  else                 { W = Wc; WT = WcT;                        Nw = 2048; t = tb2 - 1536; }
  int ntiles = Nw >> 6;
  int n0 = (t % ntiles) * 64, k0 = (t / ntiles) * 64;
#pragma unroll
  for (int i = 0; i < 16; i++) {
    int idx = i * 256 + tid;
    int r = idx >> 6, c = idx & 63;
    tile[r][c] = W[(size_t)(k0 + r) * Nw + n0 + c];
  }
  __syncthreads();
#pragma unroll
  for (int i = 0; i < 16; i++) {
    int idx = i * 256 + tid;
    int r = idx >> 6, c = idx & 63;
    WT[(size_t)(n0 + r) * 2048 + k0 + c] = f2bf(tile[c][r]);
  }
}

// ---------------- fused QKV GEMM (C^T) + RMSNorm + RoPE + head scatter ----------------
// Computes (x @ Wqkv)^T per 128x128 tile: A-operand = Wcat rows (d), B-operand = x rows
// (tokens) -> C cols = tokens, rows = d. N-tile 128 == one head.
//  q-heads (n0<2048):  RMS(in-lane+2shfl+LDS) + RoPE (reg-adjacent pairs) + 1/sqrt(D),
//                      LDS-transpose -> qb (B*H, T, D)
//  k-heads:            same, no 1/sqrt(D) -> kb (B*HKV, T, D)
//  v-heads:            direct coalesced store -> vb (B*HKV, D, T)   (C^T IS this layout)
__global__ __launch_bounds__(256) void gemm_qkv_fused(const u16* __restrict__ xb, const u16* __restrict__ Wcat,
                                                      const float* __restrict__ freqs,
                                                      u16* __restrict__ qb, u16* __restrict__ kb,
                                                      u16* __restrict__ vb) {
  __shared__ __align__(16) char smem[35840];     // [0,16K) As | [16K,32K) Bs ; epi: Tr [0,34816) | red [34816,35840)
  u16* As = (u16*)smem;                          // x rows: 128 tokens x 64 k
  u16* Bs = (u16*)(smem + 16384);                // W rows: 128 d x 64 k
  int tid = threadIdx.x;
  int w = tid >> 6, lane = tid & 63, quad = lane >> 4, lo = lane & 15;
  int wd = w >> 1, wt = w & 1;
  int m0 = blockIdx.y * 128, n0 = blockIdx.x * 128;
  int srow = w * 32 + (lane >> 3);
  int schunk = lane & 7;
  int gchunk = schunk ^ (lane >> 3);
  f32x4 acc[4][4] = {};                          // [dt][tt]
  for (int k0 = 0; k0 < 2048; k0 += 64) {
#pragma unroll
    for (int c = 0; c < 4; c++) {
      int r = srow + c * 8;
      async_cp16(&xb[(size_t)(m0 + r) * 2048 + k0 + gchunk * 8], &As[r * 64 + schunk * 8]);
      async_cp16(&Wcat[(size_t)(n0 + r) * 2048 + k0 + gchunk * 8], &Bs[r * 64 + schunk * 8]);
    }
    __syncthreads();
#pragma unroll
    for (int kk = 0; kk < 2; kk++) {
      bf16x8 wf[4], xf[4];
#pragma unroll
      for (int dt = 0; dt < 4; dt++) {
        int r = wd * 64 + dt * 16 + lo;
        wf[dt] = *(const bf16x8*)(&Bs[r * 64 + (((kk * 4 + quad) ^ (lo & 7)) << 3)]);
      }
#pragma unroll
      for (int tt = 0; tt < 4; tt++) {
        int r = wt * 64 + tt * 16 + lo;
        xf[tt] = *(const bf16x8*)(&As[r * 64 + (((kk * 4 + quad) ^ (lo & 7)) << 3)]);
      }
#pragma unroll
      for (int dt = 0; dt < 4; dt++)
#pragma unroll
        for (int tt = 0; tt < 4; tt++)
          acc[dt][tt] = __builtin_amdgcn_mfma_f32_16x16x32_bf16(wf[dt], xf[tt], acc[dt][tt], 0, 0, 0);
    }
    __syncthreads();
  }

  if (n0 >= 2560) {                      // ---- V: direct transposed store ----
    int head = (n0 - 2560) >> 7;
#pragma unroll
    for (int dt = 0; dt < 4; dt++)
#pragma unroll
      for (int tt = 0; tt < 4; tt++) {
        int g = m0 + wt * 64 + tt * 16 + lo;
        int b = g >> 11, t = g & 2047;
        size_t base = ((size_t)(b * HKV_ + head) * D_) * T_ + t;
#pragma unroll
        for (int r = 0; r < 4; r++) {
          int dd = wd * 64 + dt * 16 + quad * 4 + r;
          vb[base + (size_t)dd * T_] = f2bf(acc[dt][tt][r]);
        }
      }
    return;
  }

  // ---- Q/K: RMSNorm + RoPE ----
  int isQ = (n0 < 2048);
  int head = isQ ? (n0 >> 7) : ((n0 - 2048) >> 7);
  float* red = (float*)(smem + 34816);   // [128][2]
  float ss[4] = {0.f, 0.f, 0.f, 0.f};
#pragma unroll
  for (int tt = 0; tt < 4; tt++)
#pragma unroll
    for (int dt = 0; dt < 4; dt++)
#pragma unroll
      for (int r = 0; r < 4; r++) ss[tt] += acc[dt][tt][r] * acc[dt][tt][r];
#pragma unroll
  for (int tt = 0; tt < 4; tt++) {
    ss[tt] += __shfl_xor(ss[tt], 16, 64);
    ss[tt] += __shfl_xor(ss[tt], 32, 64);
  }
  if (quad == 0) {
#pragma unroll
    for (int tt = 0; tt < 4; tt++) red[(wt * 64 + tt * 16 + lo) * 2 + wd] = ss[tt];
  }
  __syncthreads();
  float qs = isQ ? 0.08838834764831845f : 1.0f;
  float scl[4];
#pragma unroll
  for (int tt = 0; tt < 4; tt++) {
    int tl = wt * 64 + tt * 16 + lo;
    scl[tt] = rsqrtf((red[tl * 2] + red[tl * 2 + 1]) * (1.0f / 128.0f) + 1e-6f) * qs;
  }

  u16* Tr = (u16*)smem;                  // [128 tokens][136 d-stride]
#pragma unroll
  for (int tt = 0; tt < 4; tt++) {
    int tl = wt * 64 + tt * 16 + lo;
    int t = (m0 + tl) & 2047;
#pragma unroll
    for (int dt = 0; dt < 4; dt++) {
      float4 f = *(const float4*)(freqs + (size_t)t * 128 + wd * 64 + dt * 16 + quad * 4);
      float t0 = acc[dt][tt][0] * scl[tt], t1 = acc[dt][tt][1] * scl[tt];
      unsigned pk0 = (unsigned)f2bf(t0 * f.x - t1 * f.y) | (((unsigned)f2bf(t0 * f.y + t1 * f.x)) << 16);
      t0 = acc[dt][tt][2] * scl[tt]; t1 = acc[dt][tt][3] * scl[tt];
      unsigned pk1 = (unsigned)f2bf(t0 * f.z - t1 * f.w) | (((unsigned)f2bf(t0 * f.w + t1 * f.z)) << 16);
      int dd = wd * 64 + dt * 16 + quad * 4;
      *(unsigned*)(&Tr[tl * 136 + dd]) = pk0;
      *(unsigned*)(&Tr[tl * 136 + dd + 2]) = pk1;
    }
  }
  __syncthreads();

  u16* dst = isQ ? qb : kb;
  int heads = isQ ? H_ : HKV_;
  int seg = tid & 15, r0 = tid >> 4;
#pragma unroll
  for (int j = 0; j < 8; j++) {
    int tl = r0 + j * 16;
    int g = m0 + tl;
    int b = g >> 11, t = g & 2047;
    uint4 v4 = *(const uint4*)(&Tr[tl * 136 + seg * 8]);
    *(uint4*)(&dst[((size_t)(b * heads + head) * T_ + t) * D_ + seg * 8]) = v4;
  }
}

// ---------------- GEMM: C(M,N) = A(M,K) * BT(N,K)^T, bf16 in, fp32 out ----------------
__global__ __launch_bounds__(256) void gemm_bt(const u16* __restrict__ A, const u16* __restrict__ BT,
                                               float* __restrict__ Cout, int M, int N, int K) {
  __shared__ __align__(16) u16 As[128 * 64];
  __shared__ __align__(16) u16 Bs[128 * 64];
  int tid = threadIdx.x;
  int w = tid >> 6, lane = tid & 63, quad = lane >> 4, lo = lane & 15;
  int wm = w >> 1, wn = w & 1;
  int m0 = blockIdx.y * 128, n0 = blockIdx.x * 128;
  int srow = w * 32 + (lane >> 3);
  int schunk = lane & 7;
  int gchunk = schunk ^ (lane >> 3);
  f32x4 acc[4][4] = {};
  for (int k0 = 0; k0 < K; k0 += 64) {
#pragma unroll
    for (int c = 0; c < 4; c++) {
      int r = srow + c * 8;
      async_cp16(&A[(size_t)(m0 + r) * K + k0 + gchunk * 8], &As[r * 64 + schunk * 8]);
      async_cp16(&BT[(size_t)(n0 + r) * K + k0 + gchunk * 8], &Bs[r * 64 + schunk * 8]);
    }
    __syncthreads();
#pragma unroll
    for (int kk = 0; kk < 2; kk++) {
      bf16x8 af[4], bfr[4];
#pragma unroll
      for (int mt = 0; mt < 4; mt++) {
        int r = wm * 64 + mt * 16 + lo;
        af[mt] = *(const bf16x8*)(&As[r * 64 + (((kk * 4 + quad) ^ (lo & 7)) << 3)]);
      }
#pragma unroll
      for (int nt = 0; nt < 4; nt++) {
        int r = wn * 64 + nt * 16 + lo;
        bfr[nt] = *(const bf16x8*)(&Bs[r * 64 + (((kk * 4 + quad) ^ (lo & 7)) << 3)]);
      }
#pragma unroll
      for (int mt = 0; mt < 4; mt++)
#pragma unroll
        for (int nt = 0; nt < 4; nt++)
          acc[mt][nt] = __builtin_amdgcn_mfma_f32_16x16x32_bf16(af[mt], bfr[nt], acc[mt][nt], 0, 0, 0);
    }
    __syncthreads();
  }
#pragma unroll
  for (int mt = 0; mt < 4; mt++)
#pragma unroll
    for (int nt = 0; nt < 4; nt++)
#pragma unroll
      for (int r = 0; r < 4; r++) {
        int mg = m0 + wm * 64 + mt * 16 + quad * 4 + r;
        int ng = n0 + wn * 64 + nt * 16 + lo;
        Cout[(size_t)mg * N + ng] = acc[mt][nt][r];
      }
}

// ---------------- Flash attention, causal, GQA, triangle-paired ----------------
__global__ __launch_bounds__(256) void flash_kernel(const u16* __restrict__ qb, const u16* __restrict__ kb,
                                                    const u16* __restrict__ vb, u16* __restrict__ yb) {
  __shared__ __align__(16) u16 smem[17408];
  u16* Ks = smem;              // 64 keys x 128 d, 16B chunks XOR-swizzled: chunk' = c ^ (row&7)
  u16* Vs = smem + 8192;       // 128 d x 64 keys, chunk' = c ^ (row&7)
  int bh = blockIdx.x;
  int b = bh >> 4, hq = bh & 15;
  int jp = blockIdx.y;
  int tid = threadIdx.x, w = tid >> 6, lane = tid & 63;
  int half = lane >> 5, lq = lane & 31;
  int bhkv = b * HKV_ + (hq >> 2);
  const u16* kbase = kb + (size_t)bhkv * T_ * D_;
  const u16* vbase = vb + (size_t)bhkv * D_ * T_;
  const float L2E = 1.4426950408889634f;
  const float N12 = -17.312340490667562f;

  int kchunk = lane & 15, krow0 = w * 16 + (lane >> 4);
  int vchunk = lane & 7, vrow0 = w * 32 + (lane >> 3);

  for (int ph = 0; ph < 2; ph++) {
    int qt = ph ? jp : (15 - jp);
    const u16* qbase = qb + ((size_t)bh * T_ + qt * 128) * D_;
    int qwave = qt * 128 + w * 32;

    bf16x8 qf[8];
#pragma unroll
    for (int ds = 0; ds < 8; ds++)
      qf[ds] = *(const bf16x8*)(&qbase[(w * 32 + lq) * D_ + ds * 16 + half * 8]);

    f32x16 oacc[4] = {};
    float l_part = 0.f;

    int ktmax = 2 * qt + 1;
    for (int kt = 0; kt <= ktmax; kt++) {
      const u16* ksrc = kbase + (size_t)(kt * 64) * D_;
      const u16* vsrc = vbase + kt * 64;
#pragma unroll
      for (int c = 0; c < 4; c++) {
        int r = krow0 + c * 4;
        async_cp16(&ksrc[r * D_ + ((kchunk ^ (r & 7)) << 3)], &Ks[r * 128 + (kchunk << 3)]);
      }
#pragma unroll
      for (int c = 0; c < 4; c++) {
        int r = vrow0 + c * 8;
        async_cp16(&vsrc[(size_t)r * T_ + ((vchunk ^ (r & 7)) << 3)], &Vs[r * 64 + (vchunk << 3)]);
      }
      __syncthreads();

#pragma unroll
      for (int t = 0; t < 2; t++) {
        int k0 = kt * 64 + t * 32;
        if (k0 > qwave + 31) continue;

        f32x16 s = {};
#pragma unroll
        for (int ds = 0; ds < 8; ds++) {
          bf16x8 kf = *(const bf16x8*)(&Ks[(t * 32 + lq) * 128 + ((((ds << 1) + half) ^ (lq & 7)) << 3)]);
          s = __builtin_amdgcn_mfma_f32_32x32x16_bf16(kf, qf[ds], s, 0, 0, 0);
        }

        int qglob = qwave + lq;
        if (k0 + 31 > qwave) {
#pragma unroll
          for (int i = 0; i < 16; i++) {
            int kl = k0 + 4 * half + (i & 3) + ((i >> 2) << 3);
            if (kl > qglob) s[i] = -1e30f;
          }
        }

        unsigned pd[8];
#pragma unroll
        for (int j2 = 0; j2 < 8; j2++) {
          float p0 = __builtin_amdgcn_exp2f(fmaf(s[2 * j2], L2E, N12));
          float p1 = __builtin_amdgcn_exp2f(fmaf(s[2 * j2 + 1], L2E, N12));
          l_part += p0 + p1;
          pd[j2] = __builtin_amdgcn_perm(__builtin_bit_cast(unsigned, p1),
                                         __builtin_bit_cast(unsigned, p0), 0x07060302u);
        }

        unsigned s0 = (unsigned)__shfl_xor((int)(half ? pd[0] : pd[2]), 32, 64);
        unsigned s1 = (unsigned)__shfl_xor((int)(half ? pd[1] : pd[3]), 32, 64);
        unsigned s2 = (unsigned)__shfl_xor((int)(half ? pd[4] : pd[6]), 32, 64);
        unsigned s3 = (unsigned)__shfl_xor((int)(half ? pd[5] : pd[7]), 32, 64);
        uint4 f0 = half ? uint4{s0, s1, pd[2], pd[3]} : uint4{pd[0], pd[1], s0, s1};
        uint4 f1 = half ? uint4{s2, s3, pd[6], pd[7]} : uint4{pd[4], pd[5], s2, s3};

#pragma unroll
        for (int kstep = 0; kstep < 2; kstep++) {
          uint4 fr = kstep ? f1 : f0;
          bf16x8 pf = __builtin_bit_cast(bf16x8, fr);
          int cR = (t * 2 + kstep) * 2 + half;
#pragma unroll
          for (int dt = 0; dt < 4; dt++) {
            bf16x8 vf = *(const bf16x8*)(&Vs[(dt * 32 + lq) * 64 + ((cR ^ (lq & 7)) << 3)]);
            oacc[dt] = __builtin_amdgcn_mfma_f32_32x32x16_bf16(vf, pf, oacc[dt], 0, 0, 0);
          }
        }
      }
      __syncthreads();
    }

    float lt = l_part + __shfl_xor(l_part, 32, 64);
    float inv = 1.0f / lt;

    u16* Ep = smem;
#pragma unroll
    for (int dt = 0; dt < 4; dt++)
#pragma unroll
      for (int j2 = 0; j2 < 8; j2++) {
        float p0 = oacc[dt][2 * j2] * inv;
        float p1 = oacc[dt][2 * j2 + 1] * inv;
        unsigned pk = ((unsigned)f2bf(p0)) | (((unsigned)f2bf(p1)) << 16);
        int d = dt * 32 + 4 * half + 2 * (j2 & 1) + ((j2 >> 1) << 3);
        *(unsigned*)(&Ep[(w * 32 + lq) * 136 + d]) = pk;
      }
    __syncthreads();

    int ic = tid & 15, qr0 = tid >> 4;
    size_t orow = ((size_t)b * T_ + qt * 128) * 2048 + hq * 128;
#pragma unroll
    for (int j2 = 0; j2 < 8; j2++) {
      int qr = qr0 + j2 * 16;
      uint4 v4 = *(const uint4*)(&Ep[qr * 136 + ic * 8]);
      *(uint4*)(&yb[orow + (size_t)qr * 2048 + ic * 8]) = v4;
    }
    __syncthreads();
  }
}

extern "C" void kernel_launch(void* const* d_in, const int* in_sizes, int n_in,
                              void* d_out, int out_size, void* d_ws, size_t ws_size,
                              hipStream_t stream) {
  const float* x = (const float*)d_in[0];
  const float* freqs = (const float*)d_in[1];
  const float* Wq = (const float*)d_in[2];
  const float* Wk = (const float*)d_in[3];
  const float* Wv = (const float*)d_in[4];
  const float* Wc = (const float*)d_in[5];
  float* out = (float*)d_out;

  char* ws = (char*)d_ws;
  size_t off = 0;
  auto alloc = [&](size_t bytes) { char* p = ws + off; off += (bytes + 255) & ~255ull; return p; };
  u16* xb   = (u16*)alloc((size_t)B_ * T_ * C_ * 2);
  u16* Wcat = (u16*)alloc((size_t)C_ * 3072 * 2);
  u16* WcT  = (u16*)alloc((size_t)C_ * C_ * 2);
  u16* qb   = (u16*)alloc((size_t)B_ * H_ * T_ * D_ * 2);
  u16* kb   = (u16*)alloc((size_t)B_ * HKV_ * T_ * D_ * 2);
  u16* vb   = (u16*)alloc((size_t)B_ * HKV_ * T_ * D_ * 2);
  u16* yb   = (u16*)alloc((size_t)B_ * T_ * H_ * D_ * 2);

  prep_kernel<<<dim3(4096 + 2560), dim3(256), 0, stream>>>(x, Wq, Wk, Wv, Wc, xb, Wcat, WcT);
  gemm_qkv_fused<<<dim3(24, 64), dim3(256), 0, stream>>>(xb, Wcat, freqs, qb, kb, vb);
  flash_kernel<<<dim3(B_ * H_, 8), dim3(256), 0, stream>>>(qb, kb, vb, yb);
  gemm_bt<<<dim3(16, 64), dim3(256), 0, stream>>>(yb, WcT, out, 8192, 2048, 2048);
}